// Round 2
// baseline (250.179 us; speedup 1.0000x reference)
//
#include <hip/hip_runtime.h>
#include <hip/hip_bf16.h>
#include <math.h>

// Problem constants (reference: B=64, N=512, K=32, D=64)
#define BB 64
#define NN 512
#define KK 32
#define DD 64
#define BN (BB*NN)          // 32768
#define EPSC 1e-5f
#define NEG_SLOPE 0.2f
#define NEG_INF_A (-1e9f)

// All float inputs/outputs are float32 per the reference (jnp.float32).
// R1 failed with NaN because they were read as bf16 (f32 low-half mantissa
// bits decode to bf16 Inf/NaN ~1/256 of the time).

// ---------------------------------------------------------------------------
// K0: row norms of emb_table  (nrm[n] = sqrt(sum_d emb[n,d]^2))
// ---------------------------------------------------------------------------
__global__ void k0_norms(const float* __restrict__ emb, float* __restrict__ nrm) {
    int n = threadIdx.x;            // 512 threads, 1 block
    float ss = 0.f;
    #pragma unroll
    for (int d = 0; d < DD; ++d) { float v = emb[n*DD + d]; ss += v*v; }
    nrm[n] = sqrtf(ss);
}

// ---------------------------------------------------------------------------
// K1: cosine similarity row + top-32 selection (one block per row i).
// Tie-break: larger value wins; equal values -> lower index (matches lax.top_k).
// ---------------------------------------------------------------------------
__global__ void k1_topk(const float* __restrict__ emb, const float* __restrict__ nrm,
                        int* __restrict__ topk) {
    __shared__ float wi[DD];
    __shared__ float cs[NN];
    __shared__ unsigned long long red[256];
    const int i = blockIdx.x;
    const int t = threadIdx.x;
    if (t < DD) wi[t] = emb[i*DD + t];
    __syncthreads();
    const float ni = nrm[i];
    for (int j = t; j < NN; j += 256) {
        float dot = 0.f;
        #pragma unroll
        for (int d = 0; d < DD; ++d) dot += wi[d] * emb[j*DD + d];
        cs[j] = dot / (ni * nrm[j]);
    }
    __syncthreads();
    for (int p = 0; p < KK; ++p) {
        // key: ordered-float in high bits, (N-1-j) in low bits -> max key =
        // max value, ties -> min index.
        unsigned long long best = 0ull;
        for (int j = t; j < NN; j += 256) {
            unsigned int u = __float_as_uint(cs[j]);
            u = (u & 0x80000000u) ? ~u : (u | 0x80000000u);
            unsigned long long key =
                ((unsigned long long)u << 16) | (unsigned long long)(NN - 1 - j);
            if (key > best) best = key;
        }
        red[t] = best;
        __syncthreads();
        for (int s = 128; s > 0; s >>= 1) {
            if (t < s) { if (red[t + s] > red[t]) red[t] = red[t + s]; }
            __syncthreads();
        }
        if (t == 0) {
            int idx = (NN - 1) - (int)(red[0] & 0xFFFFull);
            topk[i*KK + p] = idx;
            cs[idx] = -2.0f;        // below any cosine value
        }
        __syncthreads();
    }
}

// ---------------------------------------------------------------------------
// K2: xl = x @ lin_W^T  (one wave per row), plus per-node attention scalars:
//   si[v] = xl[v]·att_i + emb[v%N]·att_em_i
//   sj[v] = xl[v]·att_j + emb[v%N]·att_em_j
// ---------------------------------------------------------------------------
__global__ void k2_lin(const float* __restrict__ data, const float* __restrict__ emb,
                       const float* __restrict__ linW,
                       const float* __restrict__ att_i, const float* __restrict__ att_j,
                       const float* __restrict__ att_em_i, const float* __restrict__ att_em_j,
                       float* __restrict__ xl, float* __restrict__ si,
                       float* __restrict__ sj) {
    __shared__ float Wt[DD*DD];     // Wt[d][c] = lin_W[c][d]  (16 KiB)
    const int t = threadIdx.x;
    for (int idx = t; idx < DD*DD; idx += 256) {
        int d = idx >> 6, c = idx & 63;
        Wt[idx] = linW[c*DD + d];
    }
    __syncthreads();
    const int lane = t & 63;
    const int wave = t >> 6;
    const int v = blockIdx.x * 4 + wave;   // global row [0, B*N)

    float xr = data[v*DD + lane];
    float acc = 0.f;
    #pragma unroll
    for (int d = 0; d < DD; ++d) {
        float xd = __shfl(xr, d);
        acc += xd * Wt[d*DD + lane];       // consecutive -> 2-way bank (free)
    }
    xl[v*DD + lane] = acc;

    const int nloc = v & (NN - 1);
    float er = emb[nloc*DD + lane];
    float p0 = acc * att_i[lane];
    float p1 = acc * att_j[lane];
    float p2 = er  * att_em_i[lane];
    float p3 = er  * att_em_j[lane];
    #pragma unroll
    for (int m = 32; m > 0; m >>= 1) {
        p0 += __shfl_xor(p0, m);
        p1 += __shfl_xor(p1, m);
        p2 += __shfl_xor(p2, m);
        p3 += __shfl_xor(p3, m);
    }
    if (lane == 0) { si[v] = p0 + p2; sj[v] = p1 + p3; }
}

// ---------------------------------------------------------------------------
// K3: one wave per target (b,i): 33-edge softmax + aggregation + fused
// BN1/ReLU * emb / BNo / ReLU / out-projection -> out[b*N+i].
// Lane k (k<=32) owns edge k (k<32: topk neighbor, k==32: self loop).
// Lane d (0..63) owns channel d for the aggregation/epilogue.
// ---------------------------------------------------------------------------
__global__ void k3_agg(const float* __restrict__ xl, const float* __restrict__ si,
                       const float* __restrict__ sj, const int* __restrict__ topk,
                       const float* __restrict__ emb,
                       const float* __restrict__ gnn_bias,
                       const float* __restrict__ g1, const float* __restrict__ b1,
                       const float* __restrict__ m1, const float* __restrict__ v1,
                       const float* __restrict__ go, const float* __restrict__ bo,
                       const float* __restrict__ mo, const float* __restrict__ vo,
                       const float* __restrict__ outW, const float* __restrict__ outb,
                       float* __restrict__ out) {
    const int t = threadIdx.x;
    const int lane = t & 63;
    const int wave = t >> 6;
    const int tgt = blockIdx.x * 4 + wave;   // [0, B*N)
    const int b = tgt >> 9;                  // / N
    const int i = tgt & (NN - 1);

    // --- edge setup: lane k holds edge k ---
    const int k = lane;
    const bool isedge = (k <= KK);
    int tk = i;                 // default (self / unused lanes)
    bool valid = true;
    if (k < KK) { tk = topk[i*KK + k]; valid = (tk != i); }
    const int srcg = b * NN + tk;

    float a;
    if (isedge) {
        a = si[tgt] + sj[srcg];
        a = (a >= 0.f) ? a : NEG_SLOPE * a;   // leaky_relu
        if (!valid) a = NEG_INF_A;            // mask AFTER leaky (matches ref)
    } else {
        a = -3.0e38f;
    }

    float amax = a;
    #pragma unroll
    for (int m = 32; m > 0; m >>= 1) amax = fmaxf(amax, __shfl_xor(amax, m));

    float ex = (isedge && valid) ? expf(a - amax) : 0.f;
    float denom = ex;
    #pragma unroll
    for (int m = 32; m > 0; m >>= 1) denom += __shfl_xor(denom, m);
    const float alpha = ex / denom;

    // --- aggregation: lane d accumulates channel d ---
    float agg = 0.f;
    for (int kk = 0; kk <= KK; ++kk) {
        float al = __shfl(alpha, kk);   // wave-uniform
        int   sg = __shfl(srcg, kk);
        if (al != 0.f) agg += al * xl[sg*DD + lane];   // coalesced 256B/wave
    }

    // --- fused epilogue, lane d = channel d ---
    const int d = lane;
    float h = agg + gnn_bias[d];
    h = (h - m1[d]) / sqrtf(v1[d] + EPSC) * g1[d] + b1[d];
    h = fmaxf(h, 0.f);
    h *= emb[i*DD + d];
    h = (h - mo[d]) / sqrtf(vo[d] + EPSC) * go[d] + bo[d];
    h = fmaxf(h, 0.f);
    float p = h * outW[d];
    #pragma unroll
    for (int m = 32; m > 0; m >>= 1) p += __shfl_xor(p, m);
    if (lane == 0) out[tgt] = p + outb[0];
}

// ---------------------------------------------------------------------------
extern "C" void kernel_launch(void* const* d_in, const int* in_sizes, int n_in,
                              void* d_out, int out_size, void* d_ws, size_t ws_size,
                              hipStream_t stream) {
    (void)in_sizes; (void)n_in; (void)out_size; (void)ws_size;
    const float* data   = (const float*)d_in[0];
    // d_in[1] = org_edge_index (int32) — unused by the reference forward
    const float* emb    = (const float*)d_in[2];
    const float* linW   = (const float*)d_in[3];
    const float* att_i  = (const float*)d_in[4];
    const float* att_j  = (const float*)d_in[5];
    const float* attemi = (const float*)d_in[6];
    const float* attemj = (const float*)d_in[7];
    const float* gbias  = (const float*)d_in[8];
    const float* g1     = (const float*)d_in[9];
    const float* b1     = (const float*)d_in[10];
    const float* m1     = (const float*)d_in[11];
    const float* v1     = (const float*)d_in[12];
    const float* go     = (const float*)d_in[13];
    const float* bo     = (const float*)d_in[14];
    const float* mo     = (const float*)d_in[15];
    const float* vo     = (const float*)d_in[16];
    const float* outW   = (const float*)d_in[17];
    const float* outb   = (const float*)d_in[18];
    float* out = (float*)d_out;

    // Workspace layout (bytes): nrm @0 (2K), topk @4096 (64K),
    // si @128K (128K), sj @256K (128K), xl @384K (8M). Total < 9 MiB.
    char* ws = (char*)d_ws;
    float* nrm  = (float*)(ws + 0);
    int*   topk = (int*)  (ws + 4096);
    float* si   = (float*)(ws + 131072);
    float* sj   = (float*)(ws + 262144);
    float* xl   = (float*)(ws + 393216);

    k0_norms<<<1, NN, 0, stream>>>(emb, nrm);
    k1_topk<<<NN, 256, 0, stream>>>(emb, nrm, topk);
    k2_lin<<<BN/4, 256, 0, stream>>>(data, emb, linW, att_i, att_j, attemi, attemj,
                                     xl, si, sj);
    k3_agg<<<BN/4, 256, 0, stream>>>(xl, si, sj, topk, emb, gbias,
                                     g1, b1, m1, v1, go, bo, mo, vo,
                                     outW, outb, out);
}

// Round 3
// 188.244 us; speedup vs baseline: 1.3290x; 1.3290x over previous
//
#include <hip/hip_runtime.h>
#include <hip/hip_bf16.h>
#include <math.h>

// Problem constants (reference: B=64, N=512, K=32, D=64)
#define BB 64
#define NN 512
#define KK 32
#define DD 64
#define BN (BB*NN)          // 32768
#define EPSC 1e-5f
#define NEG_SLOPE 0.2f
#define NEG_INF_A (-1e9f)

// All float inputs/outputs are float32 (reference uses jnp.float32 end-to-end).

// ---------------------------------------------------------------------------
// K1: fused per-row: norms + cosine row + single-pass rank-based top-32 +
// per-node embedding attention scalars ei/ej.
// Rank selection: keys are unique (index in low bits), rank = #{key > mine};
// selected iff rank < K, written at position rank -> exactly lax.top_k order
// (value desc, index asc on ties).
// ---------------------------------------------------------------------------
__global__ void k1_topk(const float* __restrict__ emb,
                        const float* __restrict__ att_em_i,
                        const float* __restrict__ att_em_j,
                        int* __restrict__ topk,
                        float* __restrict__ ei, float* __restrict__ ej) {
    __shared__ float wi[DD];
    __shared__ float ni_s;
    __shared__ unsigned long long keys[NN];
    const int i = blockIdx.x;
    const int t = threadIdx.x;
    if (t < DD) wi[t] = emb[i*DD + t];
    __syncthreads();
    if (t < DD) {                 // t<64 == lanes 0..63 of wave 0
        float x = wi[t];
        float ss = x*x;
        float e1 = x * att_em_i[t];
        float e2 = x * att_em_j[t];
        #pragma unroll
        for (int m = 32; m > 0; m >>= 1) {
            ss += __shfl_xor(ss, m);
            e1 += __shfl_xor(e1, m);
            e2 += __shfl_xor(e2, m);
        }
        if (t == 0) { ni_s = sqrtf(ss); ei[i] = e1; ej[i] = e2; }
    }
    __syncthreads();
    const float ni = ni_s;
    for (int j = t; j < NN; j += 256) {
        float dot = 0.f, ssj = 0.f;
        #pragma unroll
        for (int d = 0; d < DD; ++d) {
            float e = emb[j*DD + d];
            dot += wi[d] * e;
            ssj += e * e;
        }
        float c = dot / (ni * sqrtf(ssj));
        unsigned int u = __float_as_uint(c);
        u = (u & 0x80000000u) ? ~u : (u | 0x80000000u);   // order-preserving bits
        keys[j] = ((unsigned long long)u << 16) | (unsigned long long)(NN - 1 - j);
    }
    __syncthreads();
    for (int j = t; j < NN; j += 256) {
        const unsigned long long mykey = keys[j];
        int rank = 0;
        #pragma unroll 8
        for (int kk = 0; kk < NN; ++kk) rank += (keys[kk] > mykey) ? 1 : 0;
        if (rank < KK) topk[i*KK + rank] = j;
    }
}

// ---------------------------------------------------------------------------
// K2: xl = x @ lin_W^T. Lane = output channel c; W[c][:] lives in 16 float4
// registers per lane (loaded once). x staged per block (16 rows, 4 KB) and
// read back as wave-uniform LDS broadcasts. No shuffles in the MAC loop.
// Also emits si/sj attention scalars using the ei/ej tables from k1.
// ---------------------------------------------------------------------------
__global__ void k2_lin(const float* __restrict__ data,
                       const float* __restrict__ linW,
                       const float* __restrict__ att_i, const float* __restrict__ att_j,
                       const float* __restrict__ ei, const float* __restrict__ ej,
                       float* __restrict__ xl, float* __restrict__ si,
                       float* __restrict__ sj) {
    __shared__ float4 xs[256];          // 16 rows x 16 float4 = 4 KiB
    const int t = threadIdx.x;
    const int lane = t & 63;
    const int wave = t >> 6;

    float4 Wr[16];                      // W[lane][0..63]
    const float4* W4 = (const float4*)linW;
    #pragma unroll
    for (int q = 0; q < 16; ++q) Wr[q] = W4[lane*16 + q];

    xs[t] = ((const float4*)data)[blockIdx.x*256 + t];   // coalesced stage
    __syncthreads();

    const int r0 = wave * 4;            // 4 rows per wave
    float acc0 = 0.f, acc1 = 0.f, acc2 = 0.f, acc3 = 0.f;
    #pragma unroll
    for (int q = 0; q < 16; ++q) {
        const float4 w = Wr[q];
        const float4 x0 = xs[(r0+0)*16 + q];   // wave-uniform -> LDS broadcast
        const float4 x1 = xs[(r0+1)*16 + q];
        const float4 x2 = xs[(r0+2)*16 + q];
        const float4 x3 = xs[(r0+3)*16 + q];
        acc0 += x0.x*w.x + x0.y*w.y + x0.z*w.z + x0.w*w.w;
        acc1 += x1.x*w.x + x1.y*w.y + x1.z*w.z + x1.w*w.w;
        acc2 += x2.x*w.x + x2.y*w.y + x2.z*w.z + x2.w*w.w;
        acc3 += x3.x*w.x + x3.y*w.y + x3.z*w.z + x3.w*w.w;
    }

    const int vbase = blockIdx.x*16 + r0;
    xl[(vbase+0)*DD + lane] = acc0;
    xl[(vbase+1)*DD + lane] = acc1;
    xl[(vbase+2)*DD + lane] = acc2;
    xl[(vbase+3)*DD + lane] = acc3;

    const float ai = att_i[lane];
    const float aj = att_j[lane];
    float accs[4] = {acc0, acc1, acc2, acc3};
    #pragma unroll
    for (int r = 0; r < 4; ++r) {
        float pi = accs[r] * ai;
        float pj = accs[r] * aj;
        #pragma unroll
        for (int m = 32; m > 0; m >>= 1) {
            pi += __shfl_xor(pi, m);
            pj += __shfl_xor(pj, m);
        }
        if (lane == 0) {
            const int v = vbase + r;
            si[v] = pi + ei[v & (NN-1)];
            sj[v] = pj + ej[v & (NN-1)];
        }
    }
}

// ---------------------------------------------------------------------------
// K3: one wave per target (b,i): 33-edge softmax + aggregation + fused
// BN1/ReLU * emb / BNo / ReLU / out-projection -> out[b*N+i].  (unchanged)
// ---------------------------------------------------------------------------
__global__ void k3_agg(const float* __restrict__ xl, const float* __restrict__ si,
                       const float* __restrict__ sj, const int* __restrict__ topk,
                       const float* __restrict__ emb,
                       const float* __restrict__ gnn_bias,
                       const float* __restrict__ g1, const float* __restrict__ b1,
                       const float* __restrict__ m1, const float* __restrict__ v1,
                       const float* __restrict__ go, const float* __restrict__ bo,
                       const float* __restrict__ mo, const float* __restrict__ vo,
                       const float* __restrict__ outW, const float* __restrict__ outb,
                       float* __restrict__ out) {
    const int t = threadIdx.x;
    const int lane = t & 63;
    const int wave = t >> 6;
    const int tgt = blockIdx.x * 4 + wave;   // [0, B*N)
    const int b = tgt >> 9;                  // / N
    const int i = tgt & (NN - 1);

    const int k = lane;
    const bool isedge = (k <= KK);
    int tk = i;
    bool valid = true;
    if (k < KK) { tk = topk[i*KK + k]; valid = (tk != i); }
    const int srcg = b * NN + tk;

    float a;
    if (isedge) {
        a = si[tgt] + sj[srcg];
        a = (a >= 0.f) ? a : NEG_SLOPE * a;   // leaky_relu
        if (!valid) a = NEG_INF_A;            // mask AFTER leaky (matches ref)
    } else {
        a = -3.0e38f;
    }

    float amax = a;
    #pragma unroll
    for (int m = 32; m > 0; m >>= 1) amax = fmaxf(amax, __shfl_xor(amax, m));

    float ex = (isedge && valid) ? expf(a - amax) : 0.f;
    float denom = ex;
    #pragma unroll
    for (int m = 32; m > 0; m >>= 1) denom += __shfl_xor(denom, m);
    const float alpha = ex / denom;

    float agg = 0.f;
    for (int kk = 0; kk <= KK; ++kk) {
        float al = __shfl(alpha, kk);
        int   sg = __shfl(srcg, kk);
        if (al != 0.f) agg += al * xl[sg*DD + lane];   // coalesced 256B/wave
    }

    const int d = lane;
    float h = agg + gnn_bias[d];
    h = (h - m1[d]) / sqrtf(v1[d] + EPSC) * g1[d] + b1[d];
    h = fmaxf(h, 0.f);
    h *= emb[i*DD + d];
    h = (h - mo[d]) / sqrtf(vo[d] + EPSC) * go[d] + bo[d];
    h = fmaxf(h, 0.f);
    float p = h * outW[d];
    #pragma unroll
    for (int m = 32; m > 0; m >>= 1) p += __shfl_xor(p, m);
    if (lane == 0) out[tgt] = p + outb[0];
}

// ---------------------------------------------------------------------------
extern "C" void kernel_launch(void* const* d_in, const int* in_sizes, int n_in,
                              void* d_out, int out_size, void* d_ws, size_t ws_size,
                              hipStream_t stream) {
    (void)in_sizes; (void)n_in; (void)out_size; (void)ws_size;
    const float* data   = (const float*)d_in[0];
    // d_in[1] = org_edge_index (int32) — unused by the reference forward
    const float* emb    = (const float*)d_in[2];
    const float* linW   = (const float*)d_in[3];
    const float* att_i  = (const float*)d_in[4];
    const float* att_j  = (const float*)d_in[5];
    const float* attemi = (const float*)d_in[6];
    const float* attemj = (const float*)d_in[7];
    const float* gbias  = (const float*)d_in[8];
    const float* g1     = (const float*)d_in[9];
    const float* b1     = (const float*)d_in[10];
    const float* m1     = (const float*)d_in[11];
    const float* v1     = (const float*)d_in[12];
    const float* go     = (const float*)d_in[13];
    const float* bo     = (const float*)d_in[14];
    const float* mo     = (const float*)d_in[15];
    const float* vo     = (const float*)d_in[16];
    const float* outW   = (const float*)d_in[17];
    const float* outb   = (const float*)d_in[18];
    float* out = (float*)d_out;

    // Workspace layout (bytes): ei @0 (2K), ej @4096 (2K), topk @8192 (64K),
    // si @128K (128K), sj @256K (128K), xl @384K (8M). Total < 9 MiB.
    char* ws = (char*)d_ws;
    float* ei   = (float*)(ws + 0);
    float* ej   = (float*)(ws + 4096);
    int*   topk = (int*)  (ws + 8192);
    float* si   = (float*)(ws + 131072);
    float* sj   = (float*)(ws + 262144);
    float* xl   = (float*)(ws + 393216);

    k1_topk<<<NN, 256, 0, stream>>>(emb, attemi, attemj, topk, ei, ej);
    k2_lin<<<BN/16, 256, 0, stream>>>(data, linW, att_i, att_j, ei, ej,
                                      xl, si, sj);
    k3_agg<<<BN/4, 256, 0, stream>>>(xl, si, sj, topk, emb, gbias,
                                     g1, b1, m1, v1, go, bo, mo, vo,
                                     outW, outb, out);
}

// Round 4
// 181.499 us; speedup vs baseline: 1.3784x; 1.0372x over previous
//
#include <hip/hip_runtime.h>
#include <hip/hip_bf16.h>
#include <math.h>

// Problem constants (reference: B=64, N=512, K=32, D=64)
#define BB 64
#define NN 512
#define KK 32
#define DD 64
#define BN (BB*NN)          // 32768
#define EPSC 1e-5f
#define NEG_SLOPE 0.2f
#define NEG_INF_A (-1e9f)

typedef unsigned long long ull;

// All float inputs/outputs are float32 (reference uses jnp.float32 end-to-end).

// ---------------------------------------------------------------------------
// K1: per row i: norm + ei/ej scalars + coalesced cosine row + single-pass
// rank-based top-32. Lane layout for cosine: (j-pair, d-half) -> coalesced
// 128B segments instead of R3's 64-distinct-line scalar reads.
// Block 0 additionally folds the BN constants for k3's epilogue.
// ---------------------------------------------------------------------------
__global__ void k1_topk(const float* __restrict__ emb,
                        const float* __restrict__ att_em_i,
                        const float* __restrict__ att_em_j,
                        const float* __restrict__ gnn_bias,
                        const float* __restrict__ g1, const float* __restrict__ b1,
                        const float* __restrict__ m1, const float* __restrict__ v1,
                        const float* __restrict__ go, const float* __restrict__ bo,
                        const float* __restrict__ mo, const float* __restrict__ vo,
                        int* __restrict__ topk,
                        float* __restrict__ ei, float* __restrict__ ej,
                        float* __restrict__ epi) {
    __shared__ float wi[DD];
    __shared__ float ni_inv_s;
    __shared__ ull keys[NN];
    const int i = blockIdx.x;
    const int t = threadIdx.x;
    if (t < DD) wi[t] = emb[i*DD + t];
    __syncthreads();
    if (t < DD) {                 // wave 0: norm + ei/ej reduces
        float x = wi[t];
        float ss = x*x;
        float e1 = x * att_em_i[t];
        float e2 = x * att_em_j[t];
        #pragma unroll
        for (int m = 32; m > 0; m >>= 1) {
            ss += __shfl_xor(ss, m);
            e1 += __shfl_xor(e1, m);
            e2 += __shfl_xor(e2, m);
        }
        if (t == 0) { ni_inv_s = 1.0f / sqrtf(ss); ei[i] = e1; ej[i] = e2; }
    }
    // block 0: fold BN constants for k3 epilogue (independent of this block's row)
    if (i == 0 && t < DD) {
        float s1 = g1[t] / sqrtf(v1[t] + EPSC);
        float B1 = (gnn_bias[t] - m1[t]) * s1 + b1[t];
        float so = go[t] / sqrtf(vo[t] + EPSC);
        float Bo = bo[t] - mo[t] * so;
        epi[t] = s1; epi[DD + t] = B1; epi[2*DD + t] = so; epi[3*DD + t] = Bo;
    }
    __syncthreads();
    const float niv = ni_inv_s;
    const int lane = t & 63;
    const int wave = t >> 6;
    const int dh = lane & 31;       // d in [0,32)
    const int jh = lane >> 5;       // which j of the pair
    const float wa = wi[dh], wb = wi[dh + 32];
    for (int p = 0; p < 64; ++p) {
        const int j = wave*128 + p*2 + jh;
        const float e0 = emb[j*DD + dh];        // lanes 0-31: row j0 [0..128B)
        const float e1 = emb[j*DD + 32 + dh];   // coalesced segments
        float dot = wa*e0 + wb*e1;
        float ss  = e0*e0 + e1*e1;
        #pragma unroll
        for (int m = 16; m > 0; m >>= 1) {
            dot += __shfl_xor(dot, m);
            ss  += __shfl_xor(ss, m);
        }
        if (dh == 0) {
            float c = dot * niv * rsqrtf(ss);
            unsigned int u = __float_as_uint(c);
            u = (u & 0x80000000u) ? ~u : (u | 0x80000000u);  // order-preserving
            keys[j] = ((ull)u << 16) | (ull)(NN - 1 - j);
        }
    }
    __syncthreads();
    // rank selection: keys unique (index in low bits); rank = #{key > mine};
    // selected iff rank < K at position rank -> exact lax.top_k order.
    for (int j = t; j < NN; j += 256) {
        const ull mykey = keys[j];
        int rank = 0;
        #pragma unroll 8
        for (int kk = 0; kk < NN; ++kk) rank += (keys[kk] > mykey) ? 1 : 0;
        if (rank < KK) topk[i*KK + rank] = j;
    }
}

// ---------------------------------------------------------------------------
// K2: xl = x @ lin_W^T. Lane = output channel; W rows in 16 float4 regs;
// x staged per block (16 rows) and broadcast from LDS. (unchanged from R3)
// ---------------------------------------------------------------------------
__global__ void k2_lin(const float* __restrict__ data,
                       const float* __restrict__ linW,
                       const float* __restrict__ att_i, const float* __restrict__ att_j,
                       const float* __restrict__ ei, const float* __restrict__ ej,
                       float* __restrict__ xl, float* __restrict__ si,
                       float* __restrict__ sj) {
    __shared__ float4 xs[256];          // 16 rows x 16 float4 = 4 KiB
    const int t = threadIdx.x;
    const int lane = t & 63;
    const int wave = t >> 6;

    float4 Wr[16];                      // W[lane][0..63]
    const float4* W4 = (const float4*)linW;
    #pragma unroll
    for (int q = 0; q < 16; ++q) Wr[q] = W4[lane*16 + q];

    xs[t] = ((const float4*)data)[blockIdx.x*256 + t];   // coalesced stage
    __syncthreads();

    const int r0 = wave * 4;            // 4 rows per wave
    float acc0 = 0.f, acc1 = 0.f, acc2 = 0.f, acc3 = 0.f;
    #pragma unroll
    for (int q = 0; q < 16; ++q) {
        const float4 w = Wr[q];
        const float4 x0 = xs[(r0+0)*16 + q];   // wave-uniform -> LDS broadcast
        const float4 x1 = xs[(r0+1)*16 + q];
        const float4 x2 = xs[(r0+2)*16 + q];
        const float4 x3 = xs[(r0+3)*16 + q];
        acc0 += x0.x*w.x + x0.y*w.y + x0.z*w.z + x0.w*w.w;
        acc1 += x1.x*w.x + x1.y*w.y + x1.z*w.z + x1.w*w.w;
        acc2 += x2.x*w.x + x2.y*w.y + x2.z*w.z + x2.w*w.w;
        acc3 += x3.x*w.x + x3.y*w.y + x3.z*w.z + x3.w*w.w;
    }

    const int vbase = blockIdx.x*16 + r0;
    xl[(vbase+0)*DD + lane] = acc0;
    xl[(vbase+1)*DD + lane] = acc1;
    xl[(vbase+2)*DD + lane] = acc2;
    xl[(vbase+3)*DD + lane] = acc3;

    const float ai = att_i[lane];
    const float aj = att_j[lane];
    float accs[4] = {acc0, acc1, acc2, acc3};
    #pragma unroll
    for (int r = 0; r < 4; ++r) {
        float pi = accs[r] * ai;
        float pj = accs[r] * aj;
        #pragma unroll
        for (int m = 32; m > 0; m >>= 1) {
            pi += __shfl_xor(pi, m);
            pj += __shfl_xor(pj, m);
        }
        if (lane == 0) {
            const int v = vbase + r;
            si[v] = pi + ei[v & (NN-1)];
            sj[v] = pj + ej[v & (NN-1)];
        }
    }
}

// ---------------------------------------------------------------------------
// K3 v2: one wave per target. Phase 1 (lane=edge, 33 edges): softmax via
// shuffle reduces, fast __expf + rcp. Phase 2 (lane=(e4,c4)): float4 gather,
// 4 edges in flight per load instruction, branch-free unrolled loop,
// butterfly e4-group reduce. Float4 epilogue with pre-folded BN constants.
// ---------------------------------------------------------------------------
__global__ void k3_agg(const float* __restrict__ xl, const float* __restrict__ si,
                       const float* __restrict__ sj, const int* __restrict__ topk,
                       const float* __restrict__ emb,
                       const float* __restrict__ epi,
                       const float* __restrict__ outW, const float* __restrict__ outb,
                       float* __restrict__ out) {
    const int t = threadIdx.x;
    const int lane = t & 63;
    const int wave = t >> 6;
    const int tgt = blockIdx.x * 4 + wave;   // [0, B*N)
    const int b = tgt >> 9;                  // / N
    const int i = tgt & (NN - 1);

    // --- phase 1: lane k (0..32) = edge ---
    const bool isedge = (lane <= KK);
    int tk = i;
    bool valid = true;
    if (lane < KK) { tk = topk[i*KK + lane]; valid = (tk != i); }
    const int srcg = b * NN + tk;

    float a;
    if (isedge) {
        a = si[tgt] + sj[srcg];
        a = (a >= 0.f) ? a : NEG_SLOPE * a;   // leaky_relu
        if (!valid) a = NEG_INF_A;            // mask AFTER leaky (matches ref)
    } else {
        a = -3.0e38f;
    }

    float amax = a;
    #pragma unroll
    for (int m = 32; m > 0; m >>= 1) amax = fmaxf(amax, __shfl_xor(amax, m));

    float ex = (isedge && valid) ? __expf(a - amax) : 0.f;
    float denom = ex;
    #pragma unroll
    for (int m = 32; m > 0; m >>= 1) denom += __shfl_xor(denom, m);
    const float alpha = ex * __builtin_amdgcn_rcpf(denom);

    // --- phase 2: float4 gather, lane = (e4 = edge subgroup, c4 = chan quad) ---
    const int c4 = lane & 15;
    const int e4 = lane >> 4;
    const float4* xl4 = (const float4*)xl;
    float4 acc = make_float4(0.f, 0.f, 0.f, 0.f);
    #pragma unroll
    for (int m = 0; m < 8; ++m) {
        const int kk = 4*m + e4;
        const float al = __shfl(alpha, kk);
        const int   sg = __shfl(srcg, kk);
        const float4 xv = xl4[sg*16 + c4];
        acc.x += al*xv.x; acc.y += al*xv.y; acc.z += al*xv.z; acc.w += al*xv.w;
    }
    {   // edge 32 (self loop): group e4==0 only
        const float al = __shfl(alpha, KK);
        const int   sg = __shfl(srcg, KK);
        if (e4 == 0) {
            const float4 xv = xl4[sg*16 + c4];
            acc.x += al*xv.x; acc.y += al*xv.y; acc.z += al*xv.z; acc.w += al*xv.w;
        }
    }
    // butterfly over the 4 e4 groups -> every lane has full channel-quad sums
    #pragma unroll
    for (int m = 16; m <= 32; m <<= 1) {
        acc.x += __shfl_xor(acc.x, m);
        acc.y += __shfl_xor(acc.y, m);
        acc.z += __shfl_xor(acc.z, m);
        acc.w += __shfl_xor(acc.w, m);
    }

    // --- float4 epilogue with folded BN constants ---
    const float4* epi4 = (const float4*)epi;
    const float4 s1 = epi4[c4];
    const float4 B1 = epi4[16 + c4];
    const float4 so = epi4[32 + c4];
    const float4 Bo = epi4[48 + c4];
    const float4 em = ((const float4*)emb)[i*16 + c4];
    const float4 w4 = ((const float4*)outW)[c4];
    float4 h;
    h.x = fmaxf(acc.x*s1.x + B1.x, 0.f) * em.x;
    h.y = fmaxf(acc.y*s1.y + B1.y, 0.f) * em.y;
    h.z = fmaxf(acc.z*s1.z + B1.z, 0.f) * em.z;
    h.w = fmaxf(acc.w*s1.w + B1.w, 0.f) * em.w;
    h.x = fmaxf(h.x*so.x + Bo.x, 0.f);
    h.y = fmaxf(h.y*so.y + Bo.y, 0.f);
    h.z = fmaxf(h.z*so.z + Bo.z, 0.f);
    h.w = fmaxf(h.w*so.w + Bo.w, 0.f);
    float p = h.x*w4.x + h.y*w4.y + h.z*w4.z + h.w*w4.w;
    p += __shfl_xor(p, 1);
    p += __shfl_xor(p, 2);
    p += __shfl_xor(p, 4);
    p += __shfl_xor(p, 8);
    if (lane == 0) out[tgt] = p + outb[0];
}

// ---------------------------------------------------------------------------
extern "C" void kernel_launch(void* const* d_in, const int* in_sizes, int n_in,
                              void* d_out, int out_size, void* d_ws, size_t ws_size,
                              hipStream_t stream) {
    (void)in_sizes; (void)n_in; (void)out_size; (void)ws_size;
    const float* data   = (const float*)d_in[0];
    // d_in[1] = org_edge_index (int32) — unused by the reference forward
    const float* emb    = (const float*)d_in[2];
    const float* linW   = (const float*)d_in[3];
    const float* att_i  = (const float*)d_in[4];
    const float* att_j  = (const float*)d_in[5];
    const float* attemi = (const float*)d_in[6];
    const float* attemj = (const float*)d_in[7];
    const float* gbias  = (const float*)d_in[8];
    const float* g1     = (const float*)d_in[9];
    const float* b1     = (const float*)d_in[10];
    const float* m1     = (const float*)d_in[11];
    const float* v1     = (const float*)d_in[12];
    const float* go     = (const float*)d_in[13];
    const float* bo     = (const float*)d_in[14];
    const float* mo     = (const float*)d_in[15];
    const float* vo     = (const float*)d_in[16];
    const float* outW   = (const float*)d_in[17];
    const float* outb   = (const float*)d_in[18];
    float* out = (float*)d_out;

    // Workspace layout (bytes): ei @0, ej @4K, epi @8K (256 f), topk @16K
    // (64K), si @128K, sj @256K, xl @384K (8M). Total < 9 MiB.
    char* ws = (char*)d_ws;
    float* ei   = (float*)(ws + 0);
    float* ej   = (float*)(ws + 4096);
    float* epi  = (float*)(ws + 8192);
    int*   topk = (int*)  (ws + 16384);
    float* si   = (float*)(ws + 131072);
    float* sj   = (float*)(ws + 262144);
    float* xl   = (float*)(ws + 393216);

    k1_topk<<<NN, 256, 0, stream>>>(emb, attemi, attemj, gbias,
                                    g1, b1, m1, v1, go, bo, mo, vo,
                                    topk, ei, ej, epi);
    k2_lin<<<BN/16, 256, 0, stream>>>(data, linW, att_i, att_j, ei, ej,
                                      xl, si, sj);
    k3_agg<<<BN/4, 256, 0, stream>>>(xl, si, sj, topk, emb, epi,
                                     outW, outb, out);
}

// Round 5
// 153.441 us; speedup vs baseline: 1.6305x; 1.1829x over previous
//
#include <hip/hip_runtime.h>
#include <hip/hip_bf16.h>
#include <math.h>

// Problem constants (reference: B=64, N=512, K=32, D=64)
#define BB 64
#define NN 512
#define KK 32
#define DD 64
#define BN (BB*NN)          // 32768
#define EPSC 1e-5f
#define NEG_SLOPE 0.2f
#define NEG_INF_A (-1e9f)

typedef unsigned long long ull;

// All float inputs/outputs are float32 (reference uses jnp.float32 end-to-end).

// ---------------------------------------------------------------------------
// K0: wave-per-row: en[i] = emb[i]/||emb[i]||, ei/ej attention scalars,
// plus folded BN epilogue constants (block 0).
// ---------------------------------------------------------------------------
__global__ void k0_prep(const float* __restrict__ emb,
                        const float* __restrict__ att_em_i,
                        const float* __restrict__ att_em_j,
                        const float* __restrict__ gnn_bias,
                        const float* __restrict__ g1, const float* __restrict__ b1,
                        const float* __restrict__ m1, const float* __restrict__ v1,
                        const float* __restrict__ go, const float* __restrict__ bo,
                        const float* __restrict__ mo, const float* __restrict__ vo,
                        float* __restrict__ en, float* __restrict__ ei,
                        float* __restrict__ ej, float* __restrict__ epi) {
    const int t = threadIdx.x;
    const int lane = t & 63;
    const int wave = t >> 6;
    const int i = blockIdx.x * 4 + wave;     // row [0, 512)
    const float x = emb[i*DD + lane];
    float ss = x*x;
    float e1 = x * att_em_i[lane];
    float e2 = x * att_em_j[lane];
    #pragma unroll
    for (int m = 32; m > 0; m >>= 1) {
        ss += __shfl_xor(ss, m);
        e1 += __shfl_xor(e1, m);
        e2 += __shfl_xor(e2, m);
    }
    en[i*DD + lane] = x * rsqrtf(ss);
    if (lane == 0) { ei[i] = e1; ej[i] = e2; }
    if (blockIdx.x == 0 && t < DD) {         // fold BN constants for k3
        float s1 = g1[t] / sqrtf(v1[t] + EPSC);
        float B1 = (gnn_bias[t] - m1[t]) * s1 + b1[t];
        float so = go[t] / sqrtf(vo[t] + EPSC);
        float Bo = bo[t] - mo[t] * so;
        epi[t] = s1; epi[DD + t] = B1; epi[2*DD + t] = so; epi[3*DD + t] = Bo;
    }
}

// ---------------------------------------------------------------------------
// KA: cos = en @ en^T, emitted as order-preserving 64-bit keys.
// k2_lin pattern: lane = column (its en-row in 16 float4 regs), 16-row A-tile
// broadcast from LDS. No shuffles. Grid = 32 row-tiles x 8 col-tiles = 256.
// ---------------------------------------------------------------------------
__global__ void kA_cos(const float* __restrict__ en, ull* __restrict__ keys) {
    __shared__ float4 As[256];               // 16 rows x 16 float4 = 4 KiB
    const int t = threadIdx.x;
    const int lane = t & 63;
    const int wave = t >> 6;
    const int bi = blockIdx.x >> 3;          // row tile (16 rows)
    const int c0 = (blockIdx.x & 7) * 64;    // col tile (64 cols)
    const float4* en4 = (const float4*)en;

    float4 Wr[16];                           // en[c0+lane][:]
    #pragma unroll
    for (int q = 0; q < 16; ++q) Wr[q] = en4[(c0 + lane)*16 + q];

    As[t] = en4[bi*256 + t];                 // coalesced row-tile stage
    __syncthreads();

    #pragma unroll
    for (int r = 0; r < 4; ++r) {
        const int jr = wave*4 + r;
        float acc = 0.f;
        #pragma unroll
        for (int q = 0; q < 16; ++q) {
            const float4 a = As[jr*16 + q];  // wave-uniform -> LDS broadcast
            const float4 w = Wr[q];
            acc += a.x*w.x + a.y*w.y + a.z*w.z + a.w*w.w;
        }
        const int row = bi*16 + jr;
        const int col = c0 + lane;
        unsigned int u = __float_as_uint(acc);
        u = (u & 0x80000000u) ? ~u : (u | 0x80000000u);  // order-preserving bits
        keys[row*NN + col] = ((ull)u << 16) | (ull)(NN - 1 - col);
    }
}

// ---------------------------------------------------------------------------
// KB: rank selection, one block per row, one thread per j. Keys unique
// (index in low bits); rank = #{key > mine}; selected iff rank < K at
// position rank -> exact lax.top_k order (value desc, index asc).
// ---------------------------------------------------------------------------
__global__ void kB_rank(const ull* __restrict__ keys, int* __restrict__ topk) {
    __shared__ ull ks[NN];
    const int i = blockIdx.x;
    const int t = threadIdx.x;               // 512 threads
    ks[t] = keys[i*NN + t];
    __syncthreads();
    const ull mykey = ks[t];
    int rank = 0;
    #pragma unroll 16
    for (int kk = 0; kk < NN; ++kk) rank += (ks[kk] > mykey) ? 1 : 0;
    if (rank < KK) topk[i*KK + rank] = t;
}

// ---------------------------------------------------------------------------
// K2: xl = x @ lin_W^T. Lane = output channel; W rows in 16 float4 regs;
// x staged per block (16 rows) and broadcast from LDS. (unchanged)
// ---------------------------------------------------------------------------
__global__ void k2_lin(const float* __restrict__ data,
                       const float* __restrict__ linW,
                       const float* __restrict__ att_i, const float* __restrict__ att_j,
                       const float* __restrict__ ei, const float* __restrict__ ej,
                       float* __restrict__ xl, float* __restrict__ si,
                       float* __restrict__ sj) {
    __shared__ float4 xs[256];          // 16 rows x 16 float4 = 4 KiB
    const int t = threadIdx.x;
    const int lane = t & 63;
    const int wave = t >> 6;

    float4 Wr[16];                      // W[lane][0..63]
    const float4* W4 = (const float4*)linW;
    #pragma unroll
    for (int q = 0; q < 16; ++q) Wr[q] = W4[lane*16 + q];

    xs[t] = ((const float4*)data)[blockIdx.x*256 + t];   // coalesced stage
    __syncthreads();

    const int r0 = wave * 4;            // 4 rows per wave
    float acc0 = 0.f, acc1 = 0.f, acc2 = 0.f, acc3 = 0.f;
    #pragma unroll
    for (int q = 0; q < 16; ++q) {
        const float4 w = Wr[q];
        const float4 x0 = xs[(r0+0)*16 + q];   // wave-uniform -> LDS broadcast
        const float4 x1 = xs[(r0+1)*16 + q];
        const float4 x2 = xs[(r0+2)*16 + q];
        const float4 x3 = xs[(r0+3)*16 + q];
        acc0 += x0.x*w.x + x0.y*w.y + x0.z*w.z + x0.w*w.w;
        acc1 += x1.x*w.x + x1.y*w.y + x1.z*w.z + x1.w*w.w;
        acc2 += x2.x*w.x + x2.y*w.y + x2.z*w.z + x2.w*w.w;
        acc3 += x3.x*w.x + x3.y*w.y + x3.z*w.z + x3.w*w.w;
    }

    const int vbase = blockIdx.x*16 + r0;
    xl[(vbase+0)*DD + lane] = acc0;
    xl[(vbase+1)*DD + lane] = acc1;
    xl[(vbase+2)*DD + lane] = acc2;
    xl[(vbase+3)*DD + lane] = acc3;

    const float ai = att_i[lane];
    const float aj = att_j[lane];
    float accs[4] = {acc0, acc1, acc2, acc3};
    #pragma unroll
    for (int r = 0; r < 4; ++r) {
        float pi = accs[r] * ai;
        float pj = accs[r] * aj;
        #pragma unroll
        for (int m = 32; m > 0; m >>= 1) {
            pi += __shfl_xor(pi, m);
            pj += __shfl_xor(pj, m);
        }
        if (lane == 0) {
            const int v = vbase + r;
            si[v] = pi + ei[v & (NN-1)];
            sj[v] = pj + ej[v & (NN-1)];
        }
    }
}

// ---------------------------------------------------------------------------
// K3: one wave per target. Phase 1 (lane=edge): softmax via shuffle reduces.
// Phase 2 (lane=(e4,c4)): float4 gather, butterfly reduce, folded-BN epilogue.
// (unchanged)
// ---------------------------------------------------------------------------
__global__ void k3_agg(const float* __restrict__ xl, const float* __restrict__ si,
                       const float* __restrict__ sj, const int* __restrict__ topk,
                       const float* __restrict__ emb,
                       const float* __restrict__ epi,
                       const float* __restrict__ outW, const float* __restrict__ outb,
                       float* __restrict__ out) {
    const int t = threadIdx.x;
    const int lane = t & 63;
    const int wave = t >> 6;
    const int tgt = blockIdx.x * 4 + wave;   // [0, B*N)
    const int b = tgt >> 9;                  // / N
    const int i = tgt & (NN - 1);

    // --- phase 1: lane k (0..32) = edge ---
    const bool isedge = (lane <= KK);
    int tk = i;
    bool valid = true;
    if (lane < KK) { tk = topk[i*KK + lane]; valid = (tk != i); }
    const int srcg = b * NN + tk;

    float a;
    if (isedge) {
        a = si[tgt] + sj[srcg];
        a = (a >= 0.f) ? a : NEG_SLOPE * a;   // leaky_relu
        if (!valid) a = NEG_INF_A;            // mask AFTER leaky (matches ref)
    } else {
        a = -3.0e38f;
    }

    float amax = a;
    #pragma unroll
    for (int m = 32; m > 0; m >>= 1) amax = fmaxf(amax, __shfl_xor(amax, m));

    float ex = (isedge && valid) ? __expf(a - amax) : 0.f;
    float denom = ex;
    #pragma unroll
    for (int m = 32; m > 0; m >>= 1) denom += __shfl_xor(denom, m);
    const float alpha = ex * __builtin_amdgcn_rcpf(denom);

    // --- phase 2: float4 gather, lane = (e4 = edge subgroup, c4 = chan quad) ---
    const int c4 = lane & 15;
    const int e4 = lane >> 4;
    const float4* xl4 = (const float4*)xl;
    float4 acc = make_float4(0.f, 0.f, 0.f, 0.f);
    #pragma unroll
    for (int m = 0; m < 8; ++m) {
        const int kk = 4*m + e4;
        const float al = __shfl(alpha, kk);
        const int   sg = __shfl(srcg, kk);
        const float4 xv = xl4[sg*16 + c4];
        acc.x += al*xv.x; acc.y += al*xv.y; acc.z += al*xv.z; acc.w += al*xv.w;
    }
    {   // edge 32 (self loop): group e4==0 only
        const float al = __shfl(alpha, KK);
        const int   sg = __shfl(srcg, KK);
        if (e4 == 0) {
            const float4 xv = xl4[sg*16 + c4];
            acc.x += al*xv.x; acc.y += al*xv.y; acc.z += al*xv.z; acc.w += al*xv.w;
        }
    }
    #pragma unroll
    for (int m = 16; m <= 32; m <<= 1) {
        acc.x += __shfl_xor(acc.x, m);
        acc.y += __shfl_xor(acc.y, m);
        acc.z += __shfl_xor(acc.z, m);
        acc.w += __shfl_xor(acc.w, m);
    }

    const float4* epi4 = (const float4*)epi;
    const float4 s1 = epi4[c4];
    const float4 B1 = epi4[16 + c4];
    const float4 so = epi4[32 + c4];
    const float4 Bo = epi4[48 + c4];
    const float4 em = ((const float4*)emb)[i*16 + c4];
    const float4 w4 = ((const float4*)outW)[c4];
    float4 h;
    h.x = fmaxf(acc.x*s1.x + B1.x, 0.f) * em.x;
    h.y = fmaxf(acc.y*s1.y + B1.y, 0.f) * em.y;
    h.z = fmaxf(acc.z*s1.z + B1.z, 0.f) * em.z;
    h.w = fmaxf(acc.w*s1.w + B1.w, 0.f) * em.w;
    h.x = fmaxf(h.x*so.x + Bo.x, 0.f);
    h.y = fmaxf(h.y*so.y + Bo.y, 0.f);
    h.z = fmaxf(h.z*so.z + Bo.z, 0.f);
    h.w = fmaxf(h.w*so.w + Bo.w, 0.f);
    float p = h.x*w4.x + h.y*w4.y + h.z*w4.z + h.w*w4.w;
    p += __shfl_xor(p, 1);
    p += __shfl_xor(p, 2);
    p += __shfl_xor(p, 4);
    p += __shfl_xor(p, 8);
    if (lane == 0) out[tgt] = p + outb[0];
}

// ---------------------------------------------------------------------------
extern "C" void kernel_launch(void* const* d_in, const int* in_sizes, int n_in,
                              void* d_out, int out_size, void* d_ws, size_t ws_size,
                              hipStream_t stream) {
    (void)in_sizes; (void)n_in; (void)out_size; (void)ws_size;
    const float* data   = (const float*)d_in[0];
    // d_in[1] = org_edge_index (int32) — unused by the reference forward
    const float* emb    = (const float*)d_in[2];
    const float* linW   = (const float*)d_in[3];
    const float* att_i  = (const float*)d_in[4];
    const float* att_j  = (const float*)d_in[5];
    const float* attemi = (const float*)d_in[6];
    const float* attemj = (const float*)d_in[7];
    const float* gbias  = (const float*)d_in[8];
    const float* g1     = (const float*)d_in[9];
    const float* b1     = (const float*)d_in[10];
    const float* m1     = (const float*)d_in[11];
    const float* v1     = (const float*)d_in[12];
    const float* go     = (const float*)d_in[13];
    const float* bo     = (const float*)d_in[14];
    const float* mo     = (const float*)d_in[15];
    const float* vo     = (const float*)d_in[16];
    const float* outW   = (const float*)d_in[17];
    const float* outb   = (const float*)d_in[18];
    float* out = (float*)d_out;

    // Workspace layout (bytes), total 8.66 MB (within R4's proven envelope):
    //   ei   @ 0      (2 KB)     ej @ 4K (2 KB)     epi @ 8K (1 KB)
    //   topk @ 16K    (64 KB)    [kB -> k3]
    //   si   @ 80K    (128 KB)   [k2 -> k3]
    //   sj   @ 208K   (128 KB)   [k2 -> k3]
    //   en   @ 336K   (128 KB)   [k0 -> kA]
    //   xl   @ 464K   (8 MB)     [k2 -> k3]
    //   keys @ 464K   (2 MB)     [kA -> kB] -- overlaps xl; dead before k2
    //                            writes xl (stream-serialized).
    char* ws = (char*)d_ws;
    float* ei   = (float*)(ws + 0);
    float* ej   = (float*)(ws + 4096);
    float* epi  = (float*)(ws + 8192);
    int*   topk = (int*)  (ws + 16384);
    float* si   = (float*)(ws + 81920);
    float* sj   = (float*)(ws + 212992);
    float* en   = (float*)(ws + 344064);
    float* xl   = (float*)(ws + 475136);
    ull*   keys = (ull*)  (ws + 475136);

    k0_prep<<<NN/4, 256, 0, stream>>>(emb, attemi, attemj, gbias,
                                      g1, b1, m1, v1, go, bo, mo, vo,
                                      en, ei, ej, epi);
    kA_cos<<<256, 256, 0, stream>>>(en, keys);
    kB_rank<<<NN, NN, 0, stream>>>(keys, topk);
    k2_lin<<<BN/16, 256, 0, stream>>>(data, linW, att_i, att_j, ei, ej,
                                      xl, si, sj);
    k3_agg<<<BN/4, 256, 0, stream>>>(xl, si, sj, topk, emb, epi,
                                     outW, outb, out);
}